// Round 7
// baseline (1688.145 us; speedup 1.0000x reference)
//
#include <hip/hip_runtime.h>

// Problem constants (from reference)
constexpr int B_ = 16, T_ = 128, S_ = 128;
constexpr int ROWS = B_ * S_;        // 2048
constexpr int NSTEPS = T_ - 1;       // 127
constexpr int TPRED = 20;
constexpr int TOUT = NSTEPS - TPRED; // 107
constexpr int RPB = 16;              // rows per pair (== MFMA M)
constexpr int TB = 512;              // 8 waves
constexpr int NBLK = 256;            // 128 pairs x 2 column-halves -> all 256 CUs

// ws layout in 4-byte units.
constexpr int OFF_HN = 0;                          // hn[2][2048][64] f16 -> 131072 dw
constexpr int OFF_HS = 131072;
constexpr int OFF_HD = 262144;                     // hd[2][2048][128] f16 -> 262144 dw
constexpr int OFF_CN = 524288;                     // cn[2][128*4][64][4] f32 (dbuf: pair reads old)
constexpr int OFF_CS = 786432;                     // cs[2][...]
constexpr int OFF_CD = 1048576;                    // cd[128*8][64][4] f32 (col-split, no race)
constexpr int OFF_OUTS = 1310720;                  // outs[127][2048][2] f32 (atomicAdd targets)
constexpr int STATE_DWORDS = OFF_OUTS + NSTEPS * ROWS * 2;  // zero h+c+outs each call
// packed fp16 weight fragments
constexpr int OFF_NPK = STATE_DWORDS;              // 16 nt * 7 tiles * 256 dw
constexpr int NPK_DW = 16 * 7 * 256;               // 28672
constexpr int OFF_SPK = OFF_NPK + NPK_DW;
constexpr int OFF_DPK = OFF_SPK + NPK_DW;          // 32 nt * 16 tiles * 256 dw
constexpr int DPK_DW = 32 * 16 * 256;              // 131072
constexpr int PACK_DWORDS = 2 * NPK_DW + DPK_DW;   // 188416

typedef _Float16 half8 __attribute__((ext_vector_type(8)));
typedef float float4v __attribute__((ext_vector_type(4)));

__device__ __forceinline__ float sigm(float x) { return 1.f / (1.f + __expf(-x)); }
__device__ __forceinline__ float tanh_(float x) { return 2.f / (1.f + __expf(-2.f * x)) - 1.f; }
__device__ __forceinline__ unsigned int pack2(float a, float b) {
    union { unsigned int u; _Float16 h[2]; } x;
    x.h[0] = (_Float16)a; x.h[1] = (_Float16)b; return x.u;
}

// ---- pack fp32 weights into MFMA B-fragment tiles (fp16), once per call ----
// B-frag for 16x16x32: lane l holds B[k=(l>>4)*8+j][n=l&15], j=0..7 -> tile = 512 f16 = 256 dw.
// n/s packs: per nt(16): [Wh kt0, Wh kt1, Wa kt0, Wa kt1, Wb kt0, Wb kt1, Xaug]
// d pack: per nt(32): [dWx kt0..3, dWh kt0..3, dWa kt0..3, dWb kt0..3]
__global__ __launch_bounds__(256) void pack_weights(
    const float* __restrict__ nWx, const float* __restrict__ nWh,
    const float* __restrict__ nWa, const float* __restrict__ nWb, const float* __restrict__ nb,
    const float* __restrict__ sWx, const float* __restrict__ sWh,
    const float* __restrict__ sWa, const float* __restrict__ sWb, const float* __restrict__ sb,
    const float* __restrict__ dWx, const float* __restrict__ dWh,
    const float* __restrict__ dWa, const float* __restrict__ dWb,
    unsigned int* __restrict__ wsu)
{
    int idx = blockIdx.x * 256 + threadIdx.x;
    if (idx >= PACK_DWORDS) return;
    if (idx < 2 * NPK_DW) {
        bool isS = idx >= NPK_DW;
        int dn = isS ? idx - NPK_DW : idx;
        int tile = dn >> 8;
        int e = (dn & 255) * 2;           // half index in tile (even)
        int lane = e >> 3, j0 = e & 7;
        int quad = lane >> 4;
        int nt = tile / 7, tt = tile % 7;
        int col = nt * 16 + (lane & 15);
        float v0, v1;
        if (tt < 6) {
            const float* W = isS ? ((tt < 2) ? sWh : (tt < 4) ? sWa : sWb)
                                 : ((tt < 2) ? nWh : (tt < 4) ? nWa : nWb);
            int k = (tt & 1) * 32 + quad * 8 + j0;
            v0 = W[k * 256 + col]; v1 = W[(k + 1) * 256 + col];
        } else {
            int kl = quad * 8 + j0;
            auto xv = [&](int k) -> float {
                if (!isS) { if (k < 3) return nWx[k * 256 + col]; if (k == 3) return nb[col]; return 0.f; }
                else      { if (k == 4) return sWx[col]; if (k == 5) return sb[col]; return 0.f; }
            };
            v0 = xv(kl); v1 = xv(kl + 1);
        }
        wsu[(isS ? OFF_SPK : OFF_NPK) + dn] = pack2(v0, v1);
    } else {
        int dd = idx - 2 * NPK_DW;
        int tile = dd >> 8;
        int e = (dd & 255) * 2;
        int lane = e >> 3, j0 = e & 7;
        int quad = lane >> 4;
        int nt = tile >> 4, tt = tile & 15;
        const float* W = (tt < 4) ? dWx : (tt < 8) ? dWh : (tt < 12) ? dWa : dWb;
        int k = (tt & 3) * 32 + quad * 8 + j0;
        int col = nt * 16 + (lane & 15);
        wsu[OFF_DPK + dd] = pack2(W[k * 512 + col], W[(k + 1) * 512 + col]);
    }
}

__global__ __launch_bounds__(TB) void step_kernel(
    int t,
    const float* __restrict__ input,
    const float* __restrict__ db,
    const float* __restrict__ onW, const float* __restrict__ osW,
    float* __restrict__ ws)
{
    const int cur = t & 1, nxt = cur ^ 1;
    _Float16* hnB = (_Float16*)((unsigned int*)ws + OFF_HN);
    _Float16* hsB = (_Float16*)((unsigned int*)ws + OFF_HS);
    _Float16* hdB = (_Float16*)((unsigned int*)ws + OFF_HD);
    const _Float16* hnC = hnB + cur * ROWS * 64;
    const _Float16* hsC = hsB + cur * ROWS * 64;
    const _Float16* hdC = hdB + cur * ROWS * 128;
    _Float16* hnN = hnB + nxt * ROWS * 64;
    _Float16* hsN = hsB + nxt * ROWS * 64;
    _Float16* hdN = hdB + nxt * ROWS * 128;
    float* cnB = ws + OFF_CN;
    float* csB = ws + OFF_CS;
    float* cd  = ws + OFF_CD;
    float* outs = ws + OFF_OUTS;

    const int tid = threadIdx.x;
    const int wave = tid >> 6, lane = tid & 63;
    const int quad = lane >> 4, l15 = lane & 15;
    const int blk = blockIdx.x;
    const int pr = blk >> 1;          // pair index: rows
    const int e = blk & 1;            // column half of the d-cell / heads
    const int r0 = pr * RPB;
    const int b = r0 >> 7;
    const int s0 = r0 & (S_ - 1);
    const bool leftOK = ((pr & 7) != 0);
    const bool rightOK = ((pr & 7) != 7);

    // padded fp16 LDS tiles
    __shared__ __align__(16) _Float16 sh_hn[18 * 72];
    __shared__ __align__(16) _Float16 sh_hs[18 * 72];
    __shared__ __align__(16) _Float16 sh_hd[18 * 136];
    __shared__ __align__(16) _Float16 sh_xa[16 * 40];   // x_aug: [x0,x1,x2,1,x3,1,0...]
    __shared__ __align__(16) _Float16 sh_dec[16 * 136]; // dec_in fp16 (phase-B A operand)
    __shared__ float sh_hdnew[16 * 64];                 // fp32, own 64-col half (heads)
    __shared__ float4v sh_pb[4 * 4 * 64];               // phase-B K-split partials (16 KB)

    // ---- stage h (+halo) as dwords into padded LDS; build x_aug ----
    for (int i = tid; i < 2304; i += TB) {
        if (i < 576) {
            int row = i >> 5, p = i & 31;
            int grow = r0 + row - 1;
            bool v = (row == 0) ? leftOK : ((row == 17) ? rightOK : true);
            unsigned int val = v ? ((const unsigned int*)hnC)[grow * 32 + p] : 0u;
            *(unsigned int*)(sh_hn + row * 72 + 2 * p) = val;
        } else if (i < 1152) {
            int j = i - 576;
            int row = j >> 5, p = j & 31;
            int grow = r0 + row - 1;
            bool v = (row == 0) ? leftOK : ((row == 17) ? rightOK : true);
            unsigned int val = v ? ((const unsigned int*)hsC)[grow * 32 + p] : 0u;
            *(unsigned int*)(sh_hs + row * 72 + 2 * p) = val;
        } else {
            int j = i - 1152;
            int row = j >> 6, p = j & 63;
            int grow = r0 + row - 1;
            bool v = (row == 0) ? leftOK : ((row == 17) ? rightOK : true);
            unsigned int val = v ? ((const unsigned int*)hdC)[grow * 64 + p] : 0u;
            *(unsigned int*)(sh_hd + row * 136 + 2 * p) = val;
        }
    }
    for (int i = tid; i < 272; i += TB) {
        int r = i / 17, d = 3 + (i % 17);
        ((unsigned int*)sh_xa)[r * 20 + d] = 0u;
    }
    if (tid < 16) {
        const float* xp = input + ((size_t)(b * T_ + t) * S_ + (s0 + tid)) * 4;
        unsigned int* row = (unsigned int*)sh_xa + tid * 20;
        row[0] = pack2(xp[0], xp[1]);
        row[1] = pack2(xp[2], 1.f);
        row[2] = pack2(xp[3], 1.f);
    }
    __syncthreads();

    // ---- phase A (duplicated in both halves): n-cell waves 0-3, s-cell waves 4-7 ----
    {
        const int w = wave & 3;
        const bool isS = (wave >= 4);
        const _Float16* hb = isS ? sh_hs : sh_hn;
        half8 ah0 = *(const half8*)(hb + (l15 + 1) * 72 + quad * 8);
        half8 ah1 = *(const half8*)(hb + (l15 + 1) * 72 + 32 + quad * 8);
        half8 aa0 = *(const half8*)(hb + (l15 + 2) * 72 + quad * 8);
        half8 aa1 = *(const half8*)(hb + (l15 + 2) * 72 + 32 + quad * 8);
        half8 ab0 = *(const half8*)(hb + (l15) * 72 + quad * 8);
        half8 ab1 = *(const half8*)(hb + (l15) * 72 + 32 + quad * 8);
        half8 ax  = *(const half8*)(sh_xa + l15 * 40 + quad * 8);
        const _Float16* pk = (const _Float16*)((const unsigned int*)ws + (isS ? OFF_SPK : OFF_NPK));
        float4v acc[4];
#pragma unroll
        for (int i = 0; i < 4; ++i) acc[i] = (float4v){0.f, 0.f, 0.f, 0.f};
#pragma unroll
        for (int i = 0; i < 4; ++i) {   // nt = w + 4*i  (i, f, u, o gate col-tiles)
            const _Float16* base = pk + (size_t)(w + 4 * i) * 7 * 512 + lane * 8;
            half8 b0 = *(const half8*)(base);
            half8 b1 = *(const half8*)(base + 512);
            half8 b2 = *(const half8*)(base + 1024);
            half8 b3 = *(const half8*)(base + 1536);
            half8 b4 = *(const half8*)(base + 2048);
            half8 b5 = *(const half8*)(base + 2560);
            half8 b6 = *(const half8*)(base + 3072);
            acc[i] = __builtin_amdgcn_mfma_f32_16x16x32_f16(ah0, b0, acc[i], 0, 0, 0);
            acc[i] = __builtin_amdgcn_mfma_f32_16x16x32_f16(ah1, b1, acc[i], 0, 0, 0);
            acc[i] = __builtin_amdgcn_mfma_f32_16x16x32_f16(aa0, b2, acc[i], 0, 0, 0);
            acc[i] = __builtin_amdgcn_mfma_f32_16x16x32_f16(aa1, b3, acc[i], 0, 0, 0);
            acc[i] = __builtin_amdgcn_mfma_f32_16x16x32_f16(ab0, b4, acc[i], 0, 0, 0);
            acc[i] = __builtin_amdgcn_mfma_f32_16x16x32_f16(ab1, b5, acc[i], 0, 0, 0);
            acc[i] = __builtin_amdgcn_mfma_f32_16x16x32_f16(ax,  b6, acc[i], 0, 0, 0);
        }
        // epilogue; c double-buffered (pair partner reads old c). e0 persists n,s state.
        float* cB = isS ? csB : cnB;
        size_t cIdx = ((size_t)(pr * 4 + w) * 64 + lane) * 4;
        float4v cold = *(const float4v*)(cB + (size_t)cur * 131072 + cIdx);
        float4v cnew;
        const int kcol = 16 * w + l15;
#pragma unroll
        for (int r = 0; r < 4; ++r) {
            float c2 = sigm(acc[1][r]) * cold[r] + sigm(acc[0][r]) * tanh_(acc[2][r]);
            float h2 = sigm(acc[3][r]) * tanh_(c2);
            cnew[r] = c2;
            int row = quad * 4 + r;
            sh_dec[row * 136 + (isS ? 64 : 0) + kcol] = (_Float16)h2;
            if (!isS) { if (e == 0) hnN[(size_t)(r0 + row) * 64 + kcol] = (_Float16)h2; }
            else      { if (e == 1) hsN[(size_t)(r0 + row) * 64 + kcol] = (_Float16)h2; }
        }
        if (e == 0) *(float4v*)(cB + (size_t)nxt * 131072 + cIdx) = cnew;
    }
    __syncthreads();

    // ---- phase B: d-cell, own 64-col half; K split across wave pairs (w, w+4) ----
    {
        const int w = wave & 3;
        const int kpart = wave >> 2;      // 0: dec@dWx + hd@dWh ; 1: hd_a@dWa + hd_b@dWb
        half8 a0[4], a1[4];
#pragma unroll
        for (int kt = 0; kt < 4; ++kt) {
            if (kpart == 0) {
                a0[kt] = *(const half8*)(sh_dec + l15 * 136 + kt * 32 + quad * 8);
                a1[kt] = *(const half8*)(sh_hd + (l15 + 1) * 136 + kt * 32 + quad * 8);
            } else {
                a0[kt] = *(const half8*)(sh_hd + (l15 + 2) * 136 + kt * 32 + quad * 8);
                a1[kt] = *(const half8*)(sh_hd + (l15) * 136 + kt * 32 + quad * 8);
            }
        }
        const _Float16* pd = (const _Float16*)((const unsigned int*)ws + OFF_DPK);
        float4v acc[4];
#pragma unroll
        for (int g = 0; g < 4; ++g) acc[g] = (float4v){0.f, 0.f, 0.f, 0.f};
#pragma unroll
        for (int g = 0; g < 4; ++g) {     // gate g, col-tile ct = 4e + w -> nt = g*8 + ct
            const _Float16* base = pd + (size_t)(g * 8 + 4 * e + w) * 16 * 512
                                      + (size_t)kpart * 8 * 512 + lane * 8;
#pragma unroll
            for (int kt = 0; kt < 4; ++kt)
                acc[g] = __builtin_amdgcn_mfma_f32_16x16x32_f16(a0[kt], *(const half8*)(base + kt * 512), acc[g], 0, 0, 0);
#pragma unroll
            for (int kt = 0; kt < 4; ++kt)
                acc[g] = __builtin_amdgcn_mfma_f32_16x16x32_f16(a1[kt], *(const half8*)(base + (4 + kt) * 512), acc[g], 0, 0, 0);
        }
        if (kpart == 1) {
#pragma unroll
            for (int g = 0; g < 4; ++g) sh_pb[(w * 4 + g) * 64 + lane] = acc[g];
        }
        __syncthreads();
        if (kpart == 0) {
#pragma unroll
            for (int g = 0; g < 4; ++g) acc[g] += sh_pb[(w * 4 + g) * 64 + lane];
            const int kd = 64 * e + 16 * w + l15;
            float bi = db[kd], bf = db[128 + kd], bu = db[256 + kd], bo = db[384 + kd];
            float* cPtr = cd + ((size_t)(pr * 8 + e * 4 + w) * 64 + lane) * 4;
            float4v cold = *(float4v*)cPtr, cnew;
#pragma unroll
            for (int r = 0; r < 4; ++r) {
                float c2 = sigm(acc[1][r] + bf) * cold[r] + sigm(acc[0][r] + bi) * tanh_(acc[2][r] + bu);
                float h2 = sigm(acc[3][r] + bo) * tanh_(c2);
                cnew[r] = c2;
                int row = quad * 4 + r;
                hdN[(size_t)(r0 + row) * 128 + kd] = (_Float16)h2;
                sh_hdnew[row * 64 + 16 * w + l15] = h2;
            }
            *(float4v*)cPtr = cnew;
        }
    }
    __syncthreads();

    // ---- output heads: partial over own 64 cols; atomicAdd into zeroed outs ----
    {
        int p = tid >> 4, l16 = tid & 15;
        int row = p >> 1, head = p & 1;
        const float* W = (head ? osW : onW) + 64 * e;
        float partial = 0.f;
#pragma unroll
        for (int k = 0; k < 64; k += 16) partial += sh_hdnew[row * 64 + k + l16] * W[k + l16];
#pragma unroll
        for (int off = 8; off; off >>= 1) partial += __shfl_down(partial, off, 16);
        if (l16 == 0) atomicAdd(&outs[((size_t)t * ROWS + (r0 + row)) * 2 + head], partial);
    }
}

// Assemble data outputs for t in [20,126]; head biases applied here.
__global__ __launch_bounds__(256) void assemble_kernel(
    const float* __restrict__ input, const float* __restrict__ ws,
    const float* __restrict__ onb, const float* __restrict__ osb,
    float* __restrict__ out)
{
    const float* outs = ws + OFF_OUTS;
    int idx = blockIdx.x * 256 + threadIdx.x;  // (b, tt, s)
    if (idx >= B_ * TOUT * S_) return;
    int s = idx & 127;
    int tmp = idx >> 7;
    int tt = tmp % TOUT;
    int b = tmp / TOUT;
    int t = tt + TPRED;
    int row = b * S_ + s;
    float ob0 = onb[0], ob1 = osb[0];
    float o0 = outs[((size_t)t * ROWS + row) * 2 + 0] + ob0;
    float o1 = outs[((size_t)t * ROWS + row) * 2 + 1] + ob1;
    float inflow = (s == 0) ? input[(((size_t)b * T_ + (t + 1)) * S_ + 0) * 4 + 1]
                            : (outs[((size_t)t * ROWS + row - 1) * 2 + 0] + ob0);
    float numc = input[(((size_t)b * T_ + t) * S_ + s) * 4 + 2] + inflow - o0;
    float spd = (s == 0) ? input[(((size_t)b * T_ + (t + 1)) * S_ + 0) * 4 + 3] : o1;
    float4 v = make_float4(o0, inflow, numc, spd);
    reinterpret_cast<float4*>(out)[idx] = v;
}

extern "C" void kernel_launch(void* const* d_in, const int* in_sizes, int n_in,
                              void* d_out, int out_size, void* d_ws, size_t ws_size,
                              hipStream_t stream) {
    const float* input = (const float*)d_in[0];
    const float* nWx = (const float*)d_in[1];
    const float* nWh = (const float*)d_in[2];
    const float* nWa = (const float*)d_in[3];
    const float* nWb = (const float*)d_in[4];
    const float* nb  = (const float*)d_in[5];
    const float* sWx = (const float*)d_in[6];
    const float* sWh = (const float*)d_in[7];
    const float* sWa = (const float*)d_in[8];
    const float* sWb = (const float*)d_in[9];
    const float* sb  = (const float*)d_in[10];
    const float* dWx = (const float*)d_in[11];
    const float* dWh = (const float*)d_in[12];
    const float* dWa = (const float*)d_in[13];
    const float* dWb = (const float*)d_in[14];
    const float* db  = (const float*)d_in[15];
    const float* onW = (const float*)d_in[16];
    const float* onb = (const float*)d_in[17];
    const float* osW = (const float*)d_in[18];
    const float* osb = (const float*)d_in[19];

    float* ws = (float*)d_ws;

    // zero h, c, and outs (outs is atomicAdd-accumulated); ws poisoned 0xAA pre-call
    hipMemsetAsync(ws, 0, (size_t)STATE_DWORDS * 4, stream);

    // pack weights into MFMA B-fragment tiles (once per call)
    pack_weights<<<dim3((PACK_DWORDS + 255) / 256), dim3(256), 0, stream>>>(
        nWx, nWh, nWa, nWb, nb, sWx, sWh, sWa, sWb, sb,
        dWx, dWh, dWa, dWb, (unsigned int*)ws);

    for (int t = 0; t < NSTEPS; ++t) {
        step_kernel<<<dim3(NBLK), dim3(TB), 0, stream>>>(
            t, input, db, onW, osW, ws);
    }

    int nout = B_ * TOUT * S_;
    assemble_kernel<<<dim3((nout + 255) / 256), dim3(256), 0, stream>>>(
        input, ws, onb, osb, (float*)d_out);
}